// Round 1
// baseline (272.262 us; speedup 1.0000x reference)
//
#include <hip/hip_runtime.h>

// FactoredQuantizer: B=8192, M=16, N=256, C=64
// inputs  [B, M, C] fp32
// codebook[M, N, C] fp32
// out = codes [B, M, C] fp32  ++  idx [B, M] (written as fp32 values)

#define BQ 8192
#define MQ 16
#define NQ 256
#define CQ 64

// ---------------------------------------------------------------------------
// Kernel 1: c2[m*N+n] = sum_k codebook[(m*N+n)*C+k]^2
// One wave per (m,n) entry, lane k holds element k, butterfly reduce.
// ---------------------------------------------------------------------------
__global__ __launch_bounds__(256) void fq_c2_kernel(
        const float* __restrict__ codebook, float* __restrict__ c2) {
    const int wave = (blockIdx.x * blockDim.x + threadIdx.x) >> 6;  // entry id
    const int lane = threadIdx.x & 63;
    float v = codebook[(size_t)wave * CQ + lane];
    float s = v * v;
    #pragma unroll
    for (int off = 32; off > 0; off >>= 1)
        s += __shfl_xor(s, off, 64);
    if (lane == 0) c2[wave] = s;
}

// ---------------------------------------------------------------------------
// Kernel 2: main quantizer. One lane per (b,m) row; wave shares m so that
// codebook / c2 loads are wave-uniform (scalarizable to s_load).
// ---------------------------------------------------------------------------
__global__ __launch_bounds__(256) void fq_main_kernel(
        const float* __restrict__ inputs,
        const float* __restrict__ codebook,
        const float* __restrict__ c2,
        float* __restrict__ out_codes,
        float* __restrict__ out_idx) {
    const int m    = blockIdx.y;
    const int wave = threadIdx.x >> 6;
    const int lane = threadIdx.x & 63;
    const int b    = blockIdx.x * 256 + wave * 64 + lane;

    // Load this row's x into registers, compute ||x||^2.
    const float* xrow = inputs + ((size_t)b * MQ + m) * CQ;
    float x[CQ];
    #pragma unroll
    for (int k = 0; k < CQ; k += 4) {
        const float4 v = *(const float4*)(xrow + k);
        x[k + 0] = v.x; x[k + 1] = v.y; x[k + 2] = v.z; x[k + 3] = v.w;
    }
    float x2 = 0.0f;
    #pragma unroll
    for (int k = 0; k < CQ; ++k) x2 = fmaf(x[k], x[k], x2);

    const float* cbm = codebook + (size_t)m * NQ * CQ;  // wave-uniform base
    const float* c2m = c2 + m * NQ;

    float best = 3.402823466e38f;
    int   bi   = 0;
    #pragma unroll 2
    for (int n = 0; n < NQ; ++n) {
        const float* cb = cbm + n * CQ;   // wave-uniform -> s_load
        float acc = 0.0f;
        #pragma unroll
        for (int k = 0; k < CQ; ++k) acc = fmaf(x[k], cb[k], acc);
        const float d = (x2 - 2.0f * acc) + c2m[n];
        if (d < best) { best = d; bi = n; }   // strict < keeps first (argmin)
    }

    // idx output (as float values)
    out_idx[(size_t)b * MQ + m] = (float)bi;

    // codes output: cooperative, coalesced. Row j's winning codeword is
    // broadcast; lane k writes element k.
    const int row_base = blockIdx.x * 256 + wave * 64;
    for (int j = 0; j < 64; ++j) {
        const int bn = __shfl(bi, j, 64);
        const int bj = row_base + j;
        out_codes[((size_t)bj * MQ + m) * CQ + lane] = cbm[(size_t)bn * CQ + lane];
    }
}

extern "C" void kernel_launch(void* const* d_in, const int* in_sizes, int n_in,
                              void* d_out, int out_size, void* d_ws, size_t ws_size,
                              hipStream_t stream) {
    const float* inputs   = (const float*)d_in[0];   // [B, M, C]
    const float* codebook = (const float*)d_in[1];   // [M, N, C]
    float* out_codes = (float*)d_out;                       // [B, M, C]
    float* out_idx   = (float*)d_out + (size_t)BQ * MQ * CQ; // [B, M]
    float* c2        = (float*)d_ws;                        // [M, N] = 16 KB

    // Kernel 1: 4096 entries, one wave each -> 1024 blocks of 256 threads.
    fq_c2_kernel<<<dim3((MQ * NQ) / 4), 256, 0, stream>>>(codebook, c2);

    // Kernel 2: grid (b-chunks of 256 rows, m), block 256 (4 waves).
    fq_main_kernel<<<dim3(BQ / 256, MQ), 256, 0, stream>>>(
        inputs, codebook, c2, out_codes, out_idx);
}

// Round 2
// 241.138 us; speedup vs baseline: 1.1291x; 1.1291x over previous
//
#include <hip/hip_runtime.h>
#include <float.h>

// FactoredQuantizer: B=8192, M=16, N=256, C=64
// inputs  [B, M, C] fp32
// codebook[M, N, C] fp32
// out = codes [B, M, C] fp32  ++  idx [B, M] (written as fp32 values)

#define BQ 8192
#define MQ 16
#define NQ 256
#define CQ 64

// ---------------------------------------------------------------------------
// Kernel 1: c2[m*N+n] = sum_k codebook[(m*N+n)*C+k]^2
// ---------------------------------------------------------------------------
__global__ __launch_bounds__(256) void fq_c2_kernel(
        const float* __restrict__ codebook, float* __restrict__ c2) {
    const int wave = (blockIdx.x * blockDim.x + threadIdx.x) >> 6;  // entry id
    const int lane = threadIdx.x & 63;
    float v = codebook[(size_t)wave * CQ + lane];
    float s = v * v;
    #pragma unroll
    for (int off = 32; off > 0; off >>= 1)
        s += __shfl_xor(s, off, 64);
    if (lane == 0) c2[wave] = s;
}

// ---------------------------------------------------------------------------
// Kernel 2: main quantizer. One lane per (b,m) row; wave shares m so that
// codebook / c2 loads are wave-uniform (scalarized to s_load).
// __launch_bounds__(256, 2): allow up to ~256 VGPR so x[64] stays resident —
// round-1 build capped at 40 VGPR and re-loaded x from global every n-iter.
// 4 independent accumulator chains hide the 4-cyc FMA dependency latency.
// ---------------------------------------------------------------------------
__global__ __launch_bounds__(256, 2) void fq_main_kernel(
        const float* __restrict__ inputs,
        const float* __restrict__ codebook,
        const float* __restrict__ c2,
        float* __restrict__ out_codes,
        float* __restrict__ out_idx) {
    const int m    = blockIdx.y;
    const int wave = threadIdx.x >> 6;
    const int lane = threadIdx.x & 63;
    const int b    = blockIdx.x * 256 + wave * 64 + lane;

    // Load this row's x into registers, compute ||x||^2.
    const float* xrow = inputs + ((size_t)b * MQ + m) * CQ;
    float x[CQ];
    #pragma unroll
    for (int k = 0; k < CQ; k += 4) {
        const float4 v = *(const float4*)(xrow + k);
        x[k + 0] = v.x; x[k + 1] = v.y; x[k + 2] = v.z; x[k + 3] = v.w;
    }
    float x2 = 0.0f;
    #pragma unroll
    for (int k = 0; k < CQ; ++k) x2 = fmaf(x[k], x[k], x2);

    const float* cbm = codebook + (size_t)m * NQ * CQ;  // wave-uniform base
    const float* c2m = c2 + m * NQ;

    float best = FLT_MAX;
    int   bi   = 0;
    for (int n0 = 0; n0 < NQ; n0 += 4) {
        const float* cb0 = cbm + (size_t)(n0 + 0) * CQ;  // wave-uniform
        const float* cb1 = cbm + (size_t)(n0 + 1) * CQ;
        const float* cb2 = cbm + (size_t)(n0 + 2) * CQ;
        const float* cb3 = cbm + (size_t)(n0 + 3) * CQ;
        float a0 = 0.0f, a1 = 0.0f, a2 = 0.0f, a3 = 0.0f;
        #pragma unroll
        for (int k = 0; k < CQ; ++k) {
            a0 = fmaf(x[k], cb0[k], a0);
            a1 = fmaf(x[k], cb1[k], a1);
            a2 = fmaf(x[k], cb2[k], a2);
            a3 = fmaf(x[k], cb3[k], a3);
        }
        const float d0 = (x2 - 2.0f * a0) + c2m[n0 + 0];
        const float d1 = (x2 - 2.0f * a1) + c2m[n0 + 1];
        const float d2 = (x2 - 2.0f * a2) + c2m[n0 + 2];
        const float d3 = (x2 - 2.0f * a3) + c2m[n0 + 3];
        // Sequential strict-< keeps the lowest index on ties (argmin).
        if (d0 < best) { best = d0; bi = n0 + 0; }
        if (d1 < best) { best = d1; bi = n0 + 1; }
        if (d2 < best) { best = d2; bi = n0 + 2; }
        if (d3 < best) { best = d3; bi = n0 + 3; }
    }

    // idx output (as float values)
    out_idx[(size_t)b * MQ + m] = (float)bi;

    // codes output: cooperative, coalesced. Row j's winning codeword index is
    // broadcast (wave-uniform); lane k writes element k -> 256B stores.
    const int row_base = blockIdx.x * 256 + wave * 64;
    for (int j = 0; j < 64; ++j) {
        const int bn = __shfl(bi, j, 64);
        const int bj = row_base + j;
        out_codes[((size_t)bj * MQ + m) * CQ + lane] = cbm[(size_t)bn * CQ + lane];
    }
}

extern "C" void kernel_launch(void* const* d_in, const int* in_sizes, int n_in,
                              void* d_out, int out_size, void* d_ws, size_t ws_size,
                              hipStream_t stream) {
    const float* inputs   = (const float*)d_in[0];   // [B, M, C]
    const float* codebook = (const float*)d_in[1];   // [M, N, C]
    float* out_codes = (float*)d_out;                        // [B, M, C]
    float* out_idx   = (float*)d_out + (size_t)BQ * MQ * CQ; // [B, M]
    float* c2        = (float*)d_ws;                         // [M, N] = 16 KB

    fq_c2_kernel<<<dim3((MQ * NQ) / 4), 256, 0, stream>>>(codebook, c2);

    fq_main_kernel<<<dim3(BQ / 256, MQ), 256, 0, stream>>>(
        inputs, codebook, c2, out_codes, out_idx);
}